// Round 1
// baseline (2611.579 us; speedup 1.0000x reference)
//
#include <hip/hip_runtime.h>
#include <math.h>

#define N_NODES 16384
#define N_EDGES 524288
#define D_FEAT  128
#define BATCH   4
#define NPTS    4096   // points per cloud
#define KSEL    2048   // selected per cloud
#define MSEL    (BATCH*KSEL)  // 8192

// ---------------- FPS: one block per cloud, 256 threads, 16 pts/thread ----
__launch_bounds__(256, 1)
__global__ void fps_kernel(const float* __restrict__ pos,
                           int* __restrict__ fp_int,
                           int* __restrict__ inv,
                           float* __restrict__ out_subx,
                           float* __restrict__ out_fp)
{
    __shared__ float spos[NPTS * 3];
    __shared__ float swv[2][4];
    __shared__ int   swi[2][4];

    const int b   = blockIdx.x;
    const int tid = threadIdx.x;

    // stage this cloud's positions in LDS (coalesced)
    const float* gp = pos + (size_t)b * NPTS * 3;
    for (int i = tid; i < NPTS * 3; i += 256) spos[i] = gp[i];
    __syncthreads();

    const int P = 16;
    float x[P], y[P], z[P], dist[P];
#pragma unroll
    for (int j = 0; j < P; ++j) {
        int li = j * 256 + tid;
        x[j] = spos[li * 3 + 0];
        y[j] = spos[li * 3 + 1];
        z[j] = spos[li * 3 + 2];
        dist[j] = 1e10f;
    }

    int cur = 0;
    for (int t = 0; t < KSEL; ++t) {
        if (tid == 0) {
            int g = b * NPTS + cur;
            int m = b * KSEL + t;
            fp_int[m] = g;
            inv[g] = m;
            out_fp[m] = (float)g;
            out_subx[m * 3 + 0] = spos[cur * 3 + 0];
            out_subx[m * 3 + 1] = spos[cur * 3 + 1];
            out_subx[m * 3 + 2] = spos[cur * 3 + 2];
        }
        float qx = spos[cur * 3 + 0];
        float qy = spos[cur * 3 + 1];
        float qz = spos[cur * 3 + 2];

        float bv = -1.0f;
        int   bi = 0x7fffffff;
#pragma unroll
        for (int j = 0; j < P; ++j) {
            // exact reference arithmetic: (dx*dx + dy*dy) + dz*dz, no fma
            float dx = __fsub_rn(x[j], qx);
            float dy = __fsub_rn(y[j], qy);
            float dz = __fsub_rn(z[j], qz);
            float dd = __fadd_rn(__fadd_rn(__fmul_rn(dx, dx), __fmul_rn(dy, dy)),
                                 __fmul_rn(dz, dz));
            float nd = fminf(dist[j], dd);
            dist[j] = nd;
            // strict > keeps smallest j (= smallest local idx for this thread)
            if (nd > bv) { bv = nd; bi = j * 256 + tid; }
        }
        // wave-64 butterfly argmax, tie -> smaller index
#pragma unroll
        for (int off = 32; off >= 1; off >>= 1) {
            float ov = __shfl_xor(bv, off, 64);
            int   oi = __shfl_xor(bi, off, 64);
            if (ov > bv || (ov == bv && oi < bi)) { bv = ov; bi = oi; }
        }
        int w   = tid >> 6;
        int par = t & 1;
        if ((tid & 63) == 0) { swv[par][w] = bv; swi[par][w] = bi; }
        __syncthreads();
        float fv = swv[par][0];
        int   fi = swi[par][0];
#pragma unroll
        for (int ww = 1; ww < 4; ++ww) {
            float ov = swv[par][ww];
            int   oi = swi[par][ww];
            if (ov > fv || (ov == fv && oi < fi)) { fv = ov; fi = oi; }
        }
        cur = fi;
    }
}

// ---------------- in-degree histogram ------------------------------------
__global__ void deg_kernel(const int* __restrict__ dst, int* __restrict__ deg)
{
    int e = blockIdx.x * blockDim.x + threadIdx.x;
    if (e < N_EDGES) atomicAdd(&deg[dst[e]], 1);
}

// ---------------- exclusive scan over deg -> row_ptr (single block) ------
__global__ void scan_kernel(const int* __restrict__ deg, int* __restrict__ row_ptr)
{
    __shared__ int part[1024];
    int tid = threadIdx.x;
    int base = tid * 16;
    int local[16];
    int s = 0;
#pragma unroll
    for (int j = 0; j < 16; ++j) { local[j] = s; s += deg[base + j]; }
    part[tid] = s;
    __syncthreads();
    for (int off = 1; off < 1024; off <<= 1) {
        int v = part[tid];
        int add = (tid >= off) ? part[tid - off] : 0;
        __syncthreads();
        part[tid] = v + add;
        __syncthreads();
    }
    int prefix = (tid == 0) ? 0 : part[tid - 1];
#pragma unroll
    for (int j = 0; j < 16; ++j) row_ptr[base + j] = prefix + local[j];
    if (tid == 1023) row_ptr[N_NODES] = part[1023];
}

// ---------------- CSR scatter ---------------------------------------------
__global__ void scatter_kernel(const int* __restrict__ src, const int* __restrict__ dst,
                               const int* __restrict__ row_ptr, int* __restrict__ cursor,
                               int* __restrict__ col)
{
    int e = blockIdx.x * blockDim.x + threadIdx.x;
    if (e < N_EDGES) {
        int d0 = dst[e];
        int r = atomicAdd(&cursor[d0], 1);
        col[row_ptr[d0] + r] = src[e];
    }
}

// ---------------- mean aggregation for sampled nodes only -----------------
// one wave per sampled node, lane handles 2 feature columns (float2)
__global__ void agg_kernel(const float* __restrict__ feat,
                           const int* __restrict__ fp_int,
                           const int* __restrict__ row_ptr,
                           const int* __restrict__ col,
                           const int* __restrict__ deg,
                           float* __restrict__ out_subfeat)
{
    int wid  = (blockIdx.x * blockDim.x + threadIdx.x) >> 6;  // 0..MSEL-1
    int lane = threadIdx.x & 63;
    if (wid >= MSEL) return;
    int v  = fp_int[wid];
    int s0 = row_ptr[v];
    int s1 = row_ptr[v + 1];
    float a0 = 0.0f, a1 = 0.0f;
    for (int e = s0; e < s1; ++e) {
        int s = col[e];
        const float2* f2 = (const float2*)(feat + (size_t)s * D_FEAT);
        float2 vv = f2[lane];
        a0 += vv.x;
        a1 += vv.y;
    }
    float dv = fmaxf((float)deg[v], 1.0f);
    float* o = out_subfeat + (size_t)wid * D_FEAT + lane * 2;
    o[0] = a0 / dv;
    o[1] = a1 / dv;
}

// ---------------- induced-subgraph edge features --------------------------
__global__ void edge_kernel(const int* __restrict__ src, const int* __restrict__ dst,
                            const int* __restrict__ inv, const float* __restrict__ subx,
                            float* __restrict__ outd, float* __restrict__ outw,
                            float* __restrict__ outm)
{
    int e = blockIdx.x * blockDim.x + threadIdx.x;
    if (e >= N_EDGES) return;
    int ls = inv[src[e]];
    int ld = inv[dst[e]];
    bool mk = (ls >= 0) && (ld >= 0);
    float dx = 0.0f, dy = 0.0f, dz = 0.0f;
    if (mk) {
        dx = __fsub_rn(subx[ld * 3 + 0], subx[ls * 3 + 0]);
        dy = __fsub_rn(subx[ld * 3 + 1], subx[ls * 3 + 1]);
        dz = __fsub_rn(subx[ld * 3 + 2], subx[ls * 3 + 2]);
    }
    float w = sqrtf(__fadd_rn(__fadd_rn(__fmul_rn(dx, dx), __fmul_rn(dy, dy)),
                              __fmul_rn(dz, dz)));
    outd[e * 3 + 0] = dx;
    outd[e * 3 + 1] = dy;
    outd[e * 3 + 2] = dz;
    outw[e] = w;
    outm[e] = mk ? 1.0f : 0.0f;
}

// ---------------- launch ---------------------------------------------------
extern "C" void kernel_launch(void* const* d_in, const int* in_sizes, int n_in,
                              void* d_out, int out_size, void* d_ws, size_t ws_size,
                              hipStream_t stream)
{
    const float* pos  = (const float*)d_in[0];   // [16384,3]
    const float* feat = (const float*)d_in[1];   // [16384,128]
    const int*   src  = (const int*)d_in[2];     // [524288]
    const int*   dst  = (const int*)d_in[3];     // [524288]

    // output layout (flat float32, reference return order)
    float* out = (float*)d_out;
    float* out_subx    = out;                              // [8192,3]
    float* out_subfeat = out_subx + (size_t)MSEL * 3;      // [8192,128]
    float* out_d       = out_subfeat + (size_t)MSEL * D_FEAT; // [524288,3]
    float* out_w       = out_d + (size_t)N_EDGES * 3;      // [524288]
    float* out_m       = out_w + (size_t)N_EDGES;          // [524288]
    float* out_fp      = out_m + (size_t)N_EDGES;          // [8192]

    // workspace layout
    int* fp_int  = (int*)d_ws;            // 8192
    int* inv     = fp_int + MSEL;         // 16384
    int* deg     = inv + N_NODES;         // 16384
    int* row_ptr = deg + N_NODES;         // 16385
    int* cursor  = row_ptr + (N_NODES+1); // 16384
    int* col     = cursor + N_NODES;      // 524288

    hipMemsetAsync(inv,    0xFF, (size_t)N_NODES * 4, stream);
    hipMemsetAsync(deg,    0,    (size_t)N_NODES * 4, stream);
    hipMemsetAsync(cursor, 0,    (size_t)N_NODES * 4, stream);

    deg_kernel<<<N_EDGES / 256, 256, 0, stream>>>(dst, deg);
    scan_kernel<<<1, 1024, 0, stream>>>(deg, row_ptr);
    scatter_kernel<<<N_EDGES / 256, 256, 0, stream>>>(src, dst, row_ptr, cursor, col);

    fps_kernel<<<BATCH, 256, 0, stream>>>(pos, fp_int, inv, out_subx, out_fp);

    agg_kernel<<<(MSEL * 64) / 256, 256, 0, stream>>>(feat, fp_int, row_ptr, col, deg,
                                                      out_subfeat);
    edge_kernel<<<N_EDGES / 256, 256, 0, stream>>>(src, dst, inv, out_subx,
                                                   out_d, out_w, out_m);
}

// Round 2
// 1272.518 us; speedup vs baseline: 2.0523x; 2.0523x over previous
//
#include <hip/hip_runtime.h>
#include <math.h>

#define N_NODES 16384
#define N_EDGES 524288
#define D_FEAT  128
#define BATCH   4
#define NPTS    4096   // points per cloud
#define KSEL    2048   // selected per cloud
#define MSEL    (BATCH*KSEL)  // 8192

// ---------------------------------------------------------------------------
// FPS: one block per cloud, 256 threads (4 waves), 16 pts/thread held in
// NAMED SCALAR registers (round-1 showed arrays spilled to scratch: 340 MB
// of HBM traffic). Reduction: DPP-based u64 packed max (val<<32 | ~idx).
// ---------------------------------------------------------------------------

#define X16(F) F(0) F(1) F(2) F(3) F(4) F(5) F(6) F(7) \
               F(8) F(9) F(10) F(11) F(12) F(13) F(14) F(15)

__device__ __forceinline__ unsigned long long dpp_max_step(unsigned long long p,
                                                           unsigned int slo,
                                                           unsigned int shi)
{
    unsigned long long s = (((unsigned long long)shi) << 32) | slo;
    return (s > p) ? s : p;
}

__launch_bounds__(256, 1)
__global__ void fps_kernel(const float* __restrict__ pos,
                           int* __restrict__ fp_int,
                           int* __restrict__ inv,
                           float* __restrict__ out_subx,
                           float* __restrict__ out_fp)
{
    __shared__ float sx[NPTS];
    __shared__ float sy[NPTS];
    __shared__ float sz[NPTS];
    __shared__ int   sel[KSEL];
    __shared__ unsigned long long pwv[2][4];

    const int b   = blockIdx.x;
    const int tid = threadIdx.x;

    // stage this cloud's positions into transposed LDS arrays
    const float* gp = pos + (size_t)b * NPTS * 3;
    for (int i = tid; i < NPTS; i += 256) {
        sx[i] = gp[3 * i + 0];
        sy[i] = gp[3 * i + 1];
        sz[i] = gp[3 * i + 2];
    }
    __syncthreads();

    // 16 points per thread in named scalars (forces register residency)
#define DECL(J) float x##J, y##J, z##J, d##J;
    X16(DECL)
#undef DECL
#define LOAD(J) { int li = (J)*256 + tid; x##J = sx[li]; y##J = sy[li]; z##J = sz[li]; d##J = 1e10f; }
    X16(LOAD)
#undef LOAD

    int cur = 0;
    for (int t = 0; t < KSEL; ++t) {
        if (tid == 0) sel[t] = cur;
        float qx = sx[cur];
        float qy = sy[cur];
        float qz = sz[cur];

        float bv = -1.0f;
        int   bi = 0x7fffffff;
        // exact reference arithmetic: (dx*dx + dy*dy) + dz*dz, no fma; fminf;
        // strict > keeps smallest index on ties (j ascending = idx ascending)
#define UPD(J) { \
        float dx = __fsub_rn(x##J, qx); \
        float dy = __fsub_rn(y##J, qy); \
        float dz = __fsub_rn(z##J, qz); \
        float dd = __fadd_rn(__fadd_rn(__fmul_rn(dx, dx), __fmul_rn(dy, dy)), \
                             __fmul_rn(dz, dz)); \
        d##J = fminf(d##J, dd); \
        if (d##J > bv) { bv = d##J; bi = (J)*256 + tid; } }
        X16(UPD)
#undef UPD

        // pack: nonneg float bits are order-preserving as unsigned;
        // tie -> larger ~idx -> smaller idx (matches argmax first-occurrence)
        unsigned long long p =
            (((unsigned long long)__float_as_uint(bv)) << 32) |
            (unsigned int)(~bi);

        // DPP wave-64 max reduce into lane 63:
        // row_shr 1,2,4,8 then row_bcast15, row_bcast31
        {
            unsigned int lo, hi, slo, shi;
#define DSTEP(CTRL) \
            lo = (unsigned int)p; hi = (unsigned int)(p >> 32); \
            slo = __builtin_amdgcn_update_dpp(0, (int)lo, CTRL, 0xf, 0xf, true); \
            shi = __builtin_amdgcn_update_dpp(0, (int)hi, CTRL, 0xf, 0xf, true); \
            p = dpp_max_step(p, slo, shi);
            DSTEP(0x111)  // row_shr:1
            DSTEP(0x112)  // row_shr:2
            DSTEP(0x114)  // row_shr:4
            DSTEP(0x118)  // row_shr:8
            DSTEP(0x142)  // row_bcast:15
            DSTEP(0x143)  // row_bcast:31
#undef DSTEP
        }

        int par = t & 1;
        if ((tid & 63) == 63) pwv[par][tid >> 6] = p;
        __syncthreads();

        unsigned long long c0 = pwv[par][0];
        unsigned long long c1 = pwv[par][1];
        unsigned long long c2 = pwv[par][2];
        unsigned long long c3 = pwv[par][3];
        unsigned long long m01 = (c0 > c1) ? c0 : c1;
        unsigned long long m23 = (c2 > c3) ? c2 : c3;
        unsigned long long mm  = (m01 > m23) ? m01 : m23;
        cur = (int)(~(unsigned int)(mm & 0xffffffffULL));
    }
    __syncthreads();

    // epilogue: write selections in parallel, coalesced
    for (int t = tid; t < KSEL; t += 256) {
        int c = sel[t];
        int g = b * NPTS + c;
        int m = b * KSEL + t;
        fp_int[m] = g;
        inv[g] = m;
        out_fp[m] = (float)g;
        out_subx[m * 3 + 0] = sx[c];
        out_subx[m * 3 + 1] = sy[c];
        out_subx[m * 3 + 2] = sz[c];
    }
}

// ---------------- in-degree histogram ------------------------------------
__global__ void deg_kernel(const int* __restrict__ dst, int* __restrict__ deg)
{
    int e = blockIdx.x * blockDim.x + threadIdx.x;
    if (e < N_EDGES) atomicAdd(&deg[dst[e]], 1);
}

// ---------------- exclusive scan over deg -> row_ptr (single block) ------
__global__ void scan_kernel(const int* __restrict__ deg, int* __restrict__ row_ptr)
{
    __shared__ int part[1024];
    int tid = threadIdx.x;
    int base = tid * 16;
    int local[16];
    int s = 0;
#pragma unroll
    for (int j = 0; j < 16; ++j) { local[j] = s; s += deg[base + j]; }
    part[tid] = s;
    __syncthreads();
    for (int off = 1; off < 1024; off <<= 1) {
        int v = part[tid];
        int add = (tid >= off) ? part[tid - off] : 0;
        __syncthreads();
        part[tid] = v + add;
        __syncthreads();
    }
    int prefix = (tid == 0) ? 0 : part[tid - 1];
#pragma unroll
    for (int j = 0; j < 16; ++j) row_ptr[base + j] = prefix + local[j];
    if (tid == 1023) row_ptr[N_NODES] = part[1023];
}

// ---------------- CSR scatter ---------------------------------------------
__global__ void scatter_kernel(const int* __restrict__ src, const int* __restrict__ dst,
                               const int* __restrict__ row_ptr, int* __restrict__ cursor,
                               int* __restrict__ col)
{
    int e = blockIdx.x * blockDim.x + threadIdx.x;
    if (e < N_EDGES) {
        int d0 = dst[e];
        int r = atomicAdd(&cursor[d0], 1);
        col[row_ptr[d0] + r] = src[e];
    }
}

// ---------------- mean aggregation for sampled nodes only -----------------
__global__ void agg_kernel(const float* __restrict__ feat,
                           const int* __restrict__ fp_int,
                           const int* __restrict__ row_ptr,
                           const int* __restrict__ col,
                           const int* __restrict__ deg,
                           float* __restrict__ out_subfeat)
{
    int wid  = (blockIdx.x * blockDim.x + threadIdx.x) >> 6;  // 0..MSEL-1
    int lane = threadIdx.x & 63;
    if (wid >= MSEL) return;
    int v  = fp_int[wid];
    int s0 = row_ptr[v];
    int s1 = row_ptr[v + 1];
    float a0 = 0.0f, a1 = 0.0f;
    for (int e = s0; e < s1; ++e) {
        int s = col[e];
        const float2* f2 = (const float2*)(feat + (size_t)s * D_FEAT);
        float2 vv = f2[lane];
        a0 += vv.x;
        a1 += vv.y;
    }
    float dv = fmaxf((float)deg[v], 1.0f);
    float* o = out_subfeat + (size_t)wid * D_FEAT + lane * 2;
    o[0] = a0 / dv;
    o[1] = a1 / dv;
}

// ---------------- induced-subgraph edge features --------------------------
__global__ void edge_kernel(const int* __restrict__ src, const int* __restrict__ dst,
                            const int* __restrict__ inv, const float* __restrict__ subx,
                            float* __restrict__ outd, float* __restrict__ outw,
                            float* __restrict__ outm)
{
    int e = blockIdx.x * blockDim.x + threadIdx.x;
    if (e >= N_EDGES) return;
    int ls = inv[src[e]];
    int ld = inv[dst[e]];
    bool mk = (ls >= 0) && (ld >= 0);
    float dx = 0.0f, dy = 0.0f, dz = 0.0f;
    if (mk) {
        dx = __fsub_rn(subx[ld * 3 + 0], subx[ls * 3 + 0]);
        dy = __fsub_rn(subx[ld * 3 + 1], subx[ls * 3 + 1]);
        dz = __fsub_rn(subx[ld * 3 + 2], subx[ls * 3 + 2]);
    }
    float w = sqrtf(__fadd_rn(__fadd_rn(__fmul_rn(dx, dx), __fmul_rn(dy, dy)),
                              __fmul_rn(dz, dz)));
    outd[e * 3 + 0] = dx;
    outd[e * 3 + 1] = dy;
    outd[e * 3 + 2] = dz;
    outw[e] = w;
    outm[e] = mk ? 1.0f : 0.0f;
}

// ---------------- launch ---------------------------------------------------
extern "C" void kernel_launch(void* const* d_in, const int* in_sizes, int n_in,
                              void* d_out, int out_size, void* d_ws, size_t ws_size,
                              hipStream_t stream)
{
    const float* pos  = (const float*)d_in[0];   // [16384,3]
    const float* feat = (const float*)d_in[1];   // [16384,128]
    const int*   src  = (const int*)d_in[2];     // [524288]
    const int*   dst  = (const int*)d_in[3];     // [524288]

    float* out = (float*)d_out;
    float* out_subx    = out;                                 // [8192,3]
    float* out_subfeat = out_subx + (size_t)MSEL * 3;         // [8192,128]
    float* out_d       = out_subfeat + (size_t)MSEL * D_FEAT; // [524288,3]
    float* out_w       = out_d + (size_t)N_EDGES * 3;         // [524288]
    float* out_m       = out_w + (size_t)N_EDGES;             // [524288]
    float* out_fp      = out_m + (size_t)N_EDGES;             // [8192]

    int* fp_int  = (int*)d_ws;            // 8192
    int* inv     = fp_int + MSEL;         // 16384
    int* deg     = inv + N_NODES;         // 16384
    int* row_ptr = deg + N_NODES;         // 16385
    int* cursor  = row_ptr + (N_NODES+1); // 16384
    int* col     = cursor + N_NODES;      // 524288

    hipMemsetAsync(inv,    0xFF, (size_t)N_NODES * 4, stream);
    hipMemsetAsync(deg,    0,    (size_t)N_NODES * 4, stream);
    hipMemsetAsync(cursor, 0,    (size_t)N_NODES * 4, stream);

    deg_kernel<<<N_EDGES / 256, 256, 0, stream>>>(dst, deg);
    scan_kernel<<<1, 1024, 0, stream>>>(deg, row_ptr);
    scatter_kernel<<<N_EDGES / 256, 256, 0, stream>>>(src, dst, row_ptr, cursor, col);

    fps_kernel<<<BATCH, 256, 0, stream>>>(pos, fp_int, inv, out_subx, out_fp);

    agg_kernel<<<(MSEL * 64) / 256, 256, 0, stream>>>(feat, fp_int, row_ptr, col, deg,
                                                      out_subfeat);
    edge_kernel<<<N_EDGES / 256, 256, 0, stream>>>(src, dst, inv, out_subx,
                                                   out_d, out_w, out_m);
}